// Round 1
// baseline (53.741 us; speedup 1.0000x reference)
//
#include <hip/hip_runtime.h>

// FOFE: y_t = ALPHA * y_{t-1} + x_t over time axis of [B=8, T=4096, D=1024] fp32.
//
// Strategy: constant-decay scan => influence of state W steps back is ALPHA^W.
// ALPHA^128 ~ 1.4e-6, so each T-chunk can be computed independently by
// re-scanning a W=128 warm-up region before the chunk (no cross-block
// communication, single pass). Read overhead (CH+W)/CH = 1.25x.
//
// Grid: B(8) x chunks(8) x d-blocks(4) = 256 blocks x 256 threads
// (1 block/CU, 4 waves/CU). Thread = one scalar d-chain; wave reads 64
// consecutive floats per t step (fully coalesced 256B).

#define ALPHA 0.9f
#define T_DIM 4096
#define D_DIM 1024
#define CH    512   // chunk length along T
#define WARM  128   // warm-up (redundant) steps before each chunk
#define DB    256   // d-values per block (= threads per block)

__global__ __launch_bounds__(256)
void fofe_kernel(const float* __restrict__ x, float* __restrict__ y) {
    const int NDB = D_DIM / DB;        // 4 d-blocks
    const int NCH = T_DIM / CH;        // 8 chunks

    int blk = blockIdx.x;
    int db  = blk % NDB;
    int ch  = (blk / NDB) % NCH;
    int b   = blk / (NDB * NCH);

    int d  = db * DB + threadIdx.x;
    int t0 = ch * CH;
    int tstart = (t0 >= WARM) ? (t0 - WARM) : 0;   // chunk 0 is exact

    const float* __restrict__ xp = x + ((size_t)b * T_DIM) * D_DIM + d;
    float*       __restrict__ yp = y + ((size_t)b * T_DIM) * D_DIM + d;

    float acc = 0.0f;

    // Warm-up: scan only, no stores.
    #pragma unroll 16
    for (int t = tstart; t < t0; ++t) {
        acc = fmaf(acc, ALPHA, xp[(size_t)t * D_DIM]);
    }

    // Main chunk: scan + store.
    #pragma unroll 16
    for (int t = t0; t < t0 + CH; ++t) {
        acc = fmaf(acc, ALPHA, xp[(size_t)t * D_DIM]);
        yp[(size_t)t * D_DIM] = acc;
    }
}

extern "C" void kernel_launch(void* const* d_in, const int* in_sizes, int n_in,
                              void* d_out, int out_size, void* d_ws, size_t ws_size,
                              hipStream_t stream) {
    const float* x = (const float*)d_in[0];
    float* y = (float*)d_out;

    const int B = 8;
    const int grid = B * (T_DIM / CH) * (D_DIM / DB);   // 256 blocks
    fofe_kernel<<<grid, DB, 0, stream>>>(x, y);
}